// Round 1
// baseline (201.402 us; speedup 1.0000x reference)
//
#include <hip/hip_runtime.h>
#include <hip/hip_bf16.h>

#define BB 2
#define TT 2048
#define CC 1024
#define HH 16
#define HDD 64

typedef __attribute__((ext_vector_type(8))) short bf16x8;
typedef __attribute__((ext_vector_type(4))) float f32x4;

static __device__ __forceinline__ unsigned short f2bf(float f) {
  union { float f; unsigned u; } v; v.f = f;
  unsigned r = v.u + 0x7fffu + ((v.u >> 16) & 1u);  // RNE
  return (unsigned short)(r >> 16);
}

static __device__ __forceinline__ unsigned fbits(float f) {
  union { float f; unsigned u; } v; v.f = f; return v.u;
}

// pack two fp32 -> two bf16 (truncate) in ONE v_perm_b32
static __device__ __forceinline__ unsigned pk_trunc(float lo, float hi) {
  return __builtin_amdgcn_perm(fbits(hi), fbits(lo), 0x07060302u);
}

// raw v_exp_f32 (args bounded; skips OCML range/subnormal fixup)
static __device__ __forceinline__ float fexp2(float x) {
#if __has_builtin(__builtin_amdgcn_exp2f)
  return __builtin_amdgcn_exp2f(x);
#else
  return exp2f(x);
#endif
}

static __device__ __forceinline__ void gload_lds16(const unsigned short* g, unsigned short* l) {
  __builtin_amdgcn_global_load_lds((const __attribute__((address_space(1))) void*)g,
                                   (__attribute__((address_space(3))) void*)l, 16, 0, 0);
}

// fp32 -> bf16 for x (4M), Wq,Wk,Wv,Wp (1M each), into contiguous dst.
__global__ __launch_bounds__(256) void convert_all(
    const float* __restrict__ x, const float* __restrict__ Wq,
    const float* __restrict__ Wk, const float* __restrict__ Wv,
    const float* __restrict__ Wp, unsigned short* __restrict__ dst)
{
  const size_t M4 = 4194304, M1 = 1048576;
  const size_t e = ((size_t)blockIdx.x * 256 + threadIdx.x) * 8;
  const float* src; size_t off;
  if (e < M4)            { src = x;  off = e; }
  else if (e < M4 + M1)  { src = Wq; off = e - M4; }
  else if (e < M4 + 2*M1){ src = Wk; off = e - M4 - M1; }
  else if (e < M4 + 3*M1){ src = Wv; off = e - M4 - 2*M1; }
  else                   { src = Wp; off = e - M4 - 3*M1; }
  float4 a = *(const float4*)(src + off);
  float4 c = *(const float4*)(src + off + 4);
  unsigned short buf[8] = {f2bf(a.x), f2bf(a.y), f2bf(a.z), f2bf(a.w),
                           f2bf(c.x), f2bf(c.y), f2bf(c.z), f2bf(c.w)};
  *(uint4*)(dst + e) = *(const uint4*)buf;
}

// ---------------------------------------------------------------------------
// R12: pipelined 2-phase GEMM core (T3-minimum recipe) for both QKV and proj.
//  - BK=64, double-buffered LDS (2x32KB), ONE raw s_barrier + ONE vmcnt(0)
//    per 64-K step: stage(next tile) issued BEFORE ds_read+32-MFMA cluster,
//    so the drain is covered by compute (old code: two full-drain
//    __syncthreads per 32-K with nothing under the load latency).
//  - T2 both-sides swizzle (chunk ^= row&7) via pre-swizzled GLOBAL source
//    (LDS dest of global_load_lds must stay linear): ds_read_b128 2-way
//    (free) instead of 16-way at the 128B row stride.
//  - raw s_barrier bracketed by "memory"-clobber asm so next-tile ds_reads /
//    stage issues cannot hoist across the cross-wave completion point.
// ---------------------------------------------------------------------------

#define GEMM128_CORE(As, Bs, Aptr, Wptr)                                        \
  const int t = threadIdx.x;                                                    \
  const int wv = __builtin_amdgcn_readfirstlane(t >> 6);                        \
  const int ln = t & 63;                                                        \
  const int l16 = ln & 15;                                                      \
  const int quad = ln >> 4;                                                     \
  const int mBase = blockIdx.x * 128;                                           \
  const int nBase = blockIdx.y * 128;                                           \
  const int wm = (wv >> 1) * 64, wn = (wv & 1) * 64;                            \
  f32x4 acc[4][4];                                                              \
  _Pragma("unroll")                                                             \
  for (int i = 0; i < 4; i++)                                                   \
    _Pragma("unroll")                                                           \
    for (int j = 0; j < 4; j++) acc[i][j] = (f32x4){0.f, 0.f, 0.f, 0.f};        \
  /* staging map: wave wv, issue i covers rows i*32+wv*8 .. +8; lane ln ->     \
     row +(ln>>3), phys chunk ln&7. Source chunk pre-swizzled by row&7. */      \
  const int rowLoc = wv * 8 + (ln >> 3);                                        \
  const int csrc = ((ln & 7) ^ (ln >> 3)) * 8;                                  \
  const unsigned short* gA = Aptr + (size_t)(mBase + rowLoc) * CC + csrc;       \
  const unsigned short* gB = Wptr + (size_t)(nBase + rowLoc) * CC + csrc;       \
  const int xq = l16 & 7;                                                       \
  const int sw0 = (quad ^ xq) * 8;                                              \
  const int sw1 = ((4 + quad) ^ xq) * 8;                                        \
  STAGE(0, 0);                                                                  \
  asm volatile("s_waitcnt vmcnt(0)" ::: "memory");                              \
  __builtin_amdgcn_s_barrier();                                                 \
  asm volatile("" ::: "memory");                                                \
  for (int kt = 0; kt < CC / 64; ++kt) {                                        \
    const int cur = kt & 1;                                                     \
    if (kt < CC / 64 - 1) STAGE(cur ^ 1, kt + 1);                               \
    bf16x8 af[2][4], bfr[2][4];                                                 \
    _Pragma("unroll")                                                           \
    for (int i = 0; i < 4; ++i) {                                               \
      af[0][i]  = *(const bf16x8*)&As[cur][wm + i * 16 + l16][sw0];             \
      af[1][i]  = *(const bf16x8*)&As[cur][wm + i * 16 + l16][sw1];             \
      bfr[0][i] = *(const bf16x8*)&Bs[cur][wn + i * 16 + l16][sw0];             \
      bfr[1][i] = *(const bf16x8*)&Bs[cur][wn + i * 16 + l16][sw1];             \
    }                                                                           \
    __builtin_amdgcn_s_setprio(1);                                              \
    _Pragma("unroll")                                                           \
    for (int kh = 0; kh < 2; ++kh)                                              \
      _Pragma("unroll")                                                         \
      for (int i = 0; i < 4; ++i)                                               \
        _Pragma("unroll")                                                       \
        for (int j = 0; j < 4; ++j)                                             \
          acc[i][j] = __builtin_amdgcn_mfma_f32_16x16x32_bf16(                  \
              af[kh][i], bfr[kh][j], acc[i][j], 0, 0, 0);                       \
    __builtin_amdgcn_s_setprio(0);                                              \
    asm volatile("s_waitcnt vmcnt(0)" ::: "memory");                            \
    __builtin_amdgcn_s_barrier();                                               \
    asm volatile("" ::: "memory");                                              \
  }

// bf16 MFMA GEMM for fused QKV.
__global__ __launch_bounds__(256) void gemm_mfma(
    const unsigned short* __restrict__ A, const unsigned short* __restrict__ W,
    const float* __restrict__ b0, const float* __restrict__ b1, const float* __restrict__ b2,
    unsigned short* __restrict__ oQ, unsigned short* __restrict__ oK,
    unsigned short* __restrict__ oVt)
{
  __shared__ unsigned short As[2][128][64];
  __shared__ unsigned short Bs[2][128][64];
#define STAGE(b, kt)                                                            \
  do {                                                                          \
    const size_t ko = (size_t)(kt) * 64;                                        \
    _Pragma("unroll")                                                           \
    for (int ii = 0; ii < 4; ++ii) {                                            \
      gload_lds16(gA + ko + (size_t)ii * 32 * CC, &As[b][ii * 32 + wv * 8][0]); \
      gload_lds16(gB + ko + (size_t)ii * 32 * CC, &Bs[b][ii * 32 + wv * 8][0]); \
    }                                                                           \
  } while (0)

  GEMM128_CORE(As, Bs, A, W)
#undef STAGE

  const int which = nBase >> 10;
  const float* bias = which == 0 ? b0 : (which == 1 ? b1 : b2);
  unsigned short* dst = which == 0 ? oQ : (which == 1 ? oK : oVt);
  const float scl = which == 0 ? 0.1803368801f : 1.0f;  // 0.125*log2(e) on Q
#pragma unroll
  for (int i = 0; i < 4; i++)
#pragma unroll
    for (int r = 0; r < 4; r++) {
      const int m = mBase + wm + i * 16 + quad * 4 + r;
      const int b = m >> 11, tp = m & 2047;
#pragma unroll
      for (int j = 0; j < 4; j++) {
        const int n = nBase + wn + j * 16 + l16;
        const int nl = n & 1023, h = nl >> 6, d = nl & 63;
        const unsigned short v = f2bf((acc[i][j][r] + bias[nl]) * scl);
        if (which < 2) dst[((size_t)(b * HH + h) * TT + tp) * HDD + d] = v;
        else           dst[((size_t)(b * HH + h) * HDD + d) * TT + tp] = v;
      }
    }
}

// Output projection: same pipelined core, fp32 epilogue. grid (32,8), 256 thr.
__global__ __launch_bounds__(256) void gemm_proj(
    const unsigned short* __restrict__ A, const unsigned short* __restrict__ W,
    const float* __restrict__ bias, float* __restrict__ out)
{
  __shared__ unsigned short As[2][128][64];
  __shared__ unsigned short Bs[2][128][64];
#define STAGE(b, kt)                                                            \
  do {                                                                          \
    const size_t ko = (size_t)(kt) * 64;                                        \
    _Pragma("unroll")                                                           \
    for (int ii = 0; ii < 4; ++ii) {                                            \
      gload_lds16(gA + ko + (size_t)ii * 32 * CC, &As[b][ii * 32 + wv * 8][0]); \
      gload_lds16(gB + ko + (size_t)ii * 32 * CC, &Bs[b][ii * 32 + wv * 8][0]); \
    }                                                                           \
  } while (0)

  GEMM128_CORE(As, Bs, A, W)
#undef STAGE

#pragma unroll
  for (int i = 0; i < 4; i++)
#pragma unroll
    for (int r = 0; r < 4; r++) {
      const int m = mBase + wm + i * 16 + quad * 4 + r;
#pragma unroll
      for (int j = 0; j < 4; j++) {
        const int n = nBase + wn + j * 16 + l16;
        out[(size_t)m * CC + n] = acc[i][j][r] + bias[n];
      }
    }
}

// MFMA bf16 flash attention — R7 paired structure (unchanged this round).
__global__ __launch_bounds__(256, 2) void attn_mfma(
    const unsigned short* __restrict__ Q, const unsigned short* __restrict__ K,
    const unsigned short* __restrict__ Vt, unsigned short* __restrict__ y)
{
  __shared__ unsigned short QP[128][72];      // Q tiles; becomes P after qfrag extract
  __shared__ unsigned short Ks[2][64][72];
  __shared__ unsigned short Vts[2][64][72];

  const int t = threadIdx.x;
  const int a = blockIdx.x;        // 0..15
  const int bh = blockIdx.y;       // 0..31
  const int wave = t >> 6;
  const int lane = t & 63;
  const int l16 = lane & 15;
  const int quad = lane >> 4;

  const size_t base = (size_t)bh * TT * HDD;
  const int qtL = a, qtH = 31 - a;
  const int qBaseL = qtL * 64, qBaseH = qtH * 64;

  // stage Q: rows 0..63 = lo tile, 64..127 = hi tile
#pragma unroll
  for (int p = 0; p < 4; p++) {
    const int c = p * 256 + t;
    const int r = c >> 3, off = (c & 7) * 8;
    const int srcRow = (r < 64) ? (qBaseL + r) : (qBaseH + r - 64);
    *(uint4*)&QP[r][off] = *(const uint4*)(Q + base + (size_t)srcRow * HDD + off);
  }

  // K/V register prefetch (tile 0)
  const int sr = t >> 2, sc = (t & 3) * 8;
  const unsigned short* kbase = K + base + (size_t)sr * HDD + sc;
  const unsigned short* vbase = Vt + base + (size_t)sr * TT + sc;
  uint4 kr0 = *(const uint4*)(kbase);
  uint4 kr1 = *(const uint4*)(kbase + 32);
  uint4 vr0 = *(const uint4*)(vbase);
  uint4 vr1 = *(const uint4*)(vbase + 32);
  __syncthreads();  // Q staged

  bf16x8 qfL0 = *(const bf16x8*)&QP[wave * 16 + l16][quad * 8];
  bf16x8 qfL1 = *(const bf16x8*)&QP[wave * 16 + l16][32 + quad * 8];
  bf16x8 qfH0 = *(const bf16x8*)&QP[64 + wave * 16 + l16][quad * 8];
  bf16x8 qfH1 = *(const bf16x8*)&QP[64 + wave * 16 + l16][32 + quad * 8];
  unsigned short (*PtH)[72] = (unsigned short (*)[72])&QP[wave * 16];
  unsigned short (*PtL)[72] = (unsigned short (*)[72])&QP[64 + wave * 16];

  float lL = 0.f, lH = 0.f;  // per-lane partial; cross-quad reduce deferred
  f32x4 OfrL[4], OfrH[4];
#pragma unroll
  for (int dt = 0; dt < 4; dt++) {
    OfrL[dt] = (f32x4){0.f, 0.f, 0.f, 0.f};
    OfrH[dt] = (f32x4){0.f, 0.f, 0.f, 0.f};
  }

  for (int kt = 0; kt <= qtH; kt++) {
    const int buf = kt & 1;
    *(uint4*)&Ks[buf][sr][sc]       = kr0;
    *(uint4*)&Ks[buf][sr][sc + 32]  = kr1;
    *(uint4*)&Vts[buf][sr][sc]      = vr0;
    *(uint4*)&Vts[buf][sr][sc + 32] = vr1;
    __syncthreads();  // ONLY barrier: commits visible; prior-buf readers done
    if (kt < qtH) {
      kr0 = *(const uint4*)(kbase + (size_t)(kt + 1) * 64 * HDD);
      kr1 = *(const uint4*)(kbase + (size_t)(kt + 1) * 64 * HDD + 32);
      vr0 = *(const uint4*)(vbase + (kt + 1) * 64);
      vr1 = *(const uint4*)(vbase + (kt + 1) * 64 + 32);
    }
    const bool doLo = (kt <= qtL);

    // S^T = K Q^T
    f32x4 StH[4], StL[4];
#pragma unroll
    for (int ct = 0; ct < 4; ct++) {
      bf16x8 a0 = *(const bf16x8*)&Ks[buf][ct * 16 + l16][quad * 8];
      bf16x8 a1 = *(const bf16x8*)&Ks[buf][ct * 16 + l16][32 + quad * 8];
      f32x4 s = (f32x4){0.f, 0.f, 0.f, 0.f};
      s = __builtin_amdgcn_mfma_f32_16x16x32_bf16(a0, qfH0, s, 0, 0, 0);
      s = __builtin_amdgcn_mfma_f32_16x16x32_bf16(a1, qfH1, s, 0, 0, 0);
      StH[ct] = s;
      if (doLo) {
        f32x4 s2 = (f32x4){0.f, 0.f, 0.f, 0.f};
        s2 = __builtin_amdgcn_mfma_f32_16x16x32_bf16(a0, qfL0, s2, 0, 0, 0);
        s2 = __builtin_amdgcn_mfma_f32_16x16x32_bf16(a1, qfL1, s2, 0, 0, 0);
        StL[ct] = s2;
      }
    }

    // softmax hi (mask only on the diagonal iteration — wave-uniform branch)
    if (kt == qtH) {
#pragma unroll
      for (int ct = 0; ct < 4; ct++) {
        float p[4];
#pragma unroll
        for (int r = 0; r < 4; r++) {
          float pv = fexp2(StH[ct][r]);
          if (ct * 16 + quad * 4 + r > wave * 16 + l16) pv = 0.f;
          p[r] = pv;
        }
        lH += (p[0] + p[1]) + (p[2] + p[3]);
        uint2 pk = {pk_trunc(p[0], p[1]), pk_trunc(p[2], p[3])};
        *(uint2*)&PtH[l16][ct * 16 + quad * 4] = pk;
      }
    } else {
#pragma unroll
      for (int ct = 0; ct < 4; ct++) {
        float p[4];
#pragma unroll
        for (int r = 0; r < 4; r++) p[r] = fexp2(StH[ct][r]);
        lH += (p[0] + p[1]) + (p[2] + p[3]);
        uint2 pk = {pk_trunc(p[0], p[1]), pk_trunc(p[2], p[3])};
        *(uint2*)&PtH[l16][ct * 16 + quad * 4] = pk;
      }
    }
    if (doLo) {
      if (kt == qtL) {
#pragma unroll
        for (int ct = 0; ct < 4; ct++) {
          float p[4];
#pragma unroll
          for (int r = 0; r < 4; r++) {
            float pv = fexp2(StL[ct][r]);
            if (ct * 16 + quad * 4 + r > wave * 16 + l16) pv = 0.f;
            p[r] = pv;
          }
          lL += (p[0] + p[1]) + (p[2] + p[3]);
          uint2 pk = {pk_trunc(p[0], p[1]), pk_trunc(p[2], p[3])};
          *(uint2*)&PtL[l16][ct * 16 + quad * 4] = pk;
        }
      } else {
#pragma unroll
        for (int ct = 0; ct < 4; ct++) {
          float p[4];
#pragma unroll
          for (int r = 0; r < 4; r++) p[r] = fexp2(StL[ct][r]);
          lL += (p[0] + p[1]) + (p[2] + p[3]);
          uint2 pk = {pk_trunc(p[0], p[1]), pk_trunc(p[2], p[3])};
          *(uint2*)&PtL[l16][ct * 16 + quad * 4] = pk;
        }
      }
    }

    // O += P V (Pt wave-private: in-wave lgkmcnt ordering, no barrier)
    bf16x8 paH0 = *(const bf16x8*)&PtH[l16][quad * 8];
    bf16x8 paH1 = *(const bf16x8*)&PtH[l16][32 + quad * 8];
    bf16x8 paL0, paL1;
    if (doLo) {
      paL0 = *(const bf16x8*)&PtL[l16][quad * 8];
      paL1 = *(const bf16x8*)&PtL[l16][32 + quad * 8];
    }
#pragma unroll
    for (int dt = 0; dt < 4; dt++) {
      bf16x8 vb0 = *(const bf16x8*)&Vts[buf][dt * 16 + l16][quad * 8];
      bf16x8 vb1 = *(const bf16x8*)&Vts[buf][dt * 16 + l16][32 + quad * 8];
      OfrH[dt] = __builtin_amdgcn_mfma_f32_16x16x32_bf16(paH0, vb0, OfrH[dt], 0, 0, 0);
      OfrH[dt] = __builtin_amdgcn_mfma_f32_16x16x32_bf16(paH1, vb1, OfrH[dt], 0, 0, 0);
      if (doLo) {
        OfrL[dt] = __builtin_amdgcn_mfma_f32_16x16x32_bf16(paL0, vb0, OfrL[dt], 0, 0, 0);
        OfrL[dt] = __builtin_amdgcn_mfma_f32_16x16x32_bf16(paL1, vb1, OfrL[dt], 0, 0, 0);
      }
    }
    // no trailing barrier: next iter commits the OTHER buffer
  }

  // deferred cross-quad l reduction
  lL += __shfl_xor(lL, 16, 64); lL += __shfl_xor(lL, 32, 64);
  lH += __shfl_xor(lH, 16, 64); lH += __shfl_xor(lH, 32, 64);

  const int b = bh >> 4, h = bh & 15;
  float lRowL[4], lRowH[4];
#pragma unroll
  for (int r = 0; r < 4; r++) {
    lRowL[r] = __shfl(lL, quad * 4 + r, 16);
    lRowH[r] = __shfl(lH, quad * 4 + r, 16);
  }
#pragma unroll
  for (int r = 0; r < 4; r++) {
    const int qL = qBaseL + wave * 16 + quad * 4 + r;
    const int qH = qBaseH + wave * 16 + quad * 4 + r;
    const float invL = 1.0f / lRowL[r];
    const float invH = 1.0f / lRowH[r];
    unsigned short* ypL = y + ((size_t)(b * TT + qL)) * CC + h * 64 + l16;
    unsigned short* ypH = y + ((size_t)(b * TT + qH)) * CC + h * 64 + l16;
#pragma unroll
    for (int dt = 0; dt < 4; dt++) {
      ypL[dt * 16] = f2bf(OfrL[dt][r] * invL);
      ypH[dt * 16] = f2bf(OfrH[dt][r] * invH);
    }
  }
}

extern "C" void kernel_launch(void* const* d_in, const int* in_sizes, int n_in,
                              void* d_out, int out_size, void* d_ws, size_t ws_size,
                              hipStream_t stream) {
  const float* x  = (const float*)d_in[0];
  const float* Wq = (const float*)d_in[1];
  const float* bq = (const float*)d_in[2];
  const float* Wk = (const float*)d_in[3];
  const float* bk = (const float*)d_in[4];
  const float* Wv = (const float*)d_in[5];
  const float* bv = (const float*)d_in[6];
  const float* Wp = (const float*)d_in[7];
  const float* bp = (const float*)d_in[8];

  const size_t M4 = 4194304, M1 = 1048576;
  unsigned short* xb   = (unsigned short*)d_ws;  // 4M
  unsigned short* wqb  = xb + M4;                // wq,wk,wv,wp contiguous
  unsigned short* wpb  = wqb + 3 * M1;
  unsigned short* wsQ  = wpb + M1;               // [B,H,T,HD] (pre-scaled)
  unsigned short* wsK  = wsQ + M4;               // [B,H,T,HD]
  unsigned short* wsVt = wsK + M4;               // [B,H,HD,T]
  unsigned short* yb   = wsVt + M4;              // [B,T,C] bf16

  convert_all<<<4096, 256, 0, stream>>>(x, Wq, Wk, Wv, Wp, xb);
  gemm_mfma<<<dim3(32, 24), 256, 0, stream>>>(xb, wqb, bq, bk, bv,
                                              wsQ, wsK, wsVt);
  attn_mfma<<<dim3(16, BB * HH), 256, 0, stream>>>(wsQ, wsK, wsVt, yb);
  gemm_proj<<<dim3(32, 8), 256, 0, stream>>>(yb, wpb, bp, (float*)d_out);
}

// Round 2
// 187.091 us; speedup vs baseline: 1.0765x; 1.0765x over previous
//
#include <hip/hip_runtime.h>
#include <hip/hip_bf16.h>

#define BB 2
#define TT 2048
#define CC 1024
#define HH 16
#define HDD 64

typedef __attribute__((ext_vector_type(8))) short bf16x8;
typedef __attribute__((ext_vector_type(4))) float f32x4;

static __device__ __forceinline__ unsigned short f2bf(float f) {
  union { float f; unsigned u; } v; v.f = f;
  unsigned r = v.u + 0x7fffu + ((v.u >> 16) & 1u);  // RNE
  return (unsigned short)(r >> 16);
}

static __device__ __forceinline__ unsigned fbits(float f) {
  union { float f; unsigned u; } v; v.f = f; return v.u;
}

// pack two fp32 -> two bf16 (truncate) in ONE v_perm_b32
static __device__ __forceinline__ unsigned pk_trunc(float lo, float hi) {
  return __builtin_amdgcn_perm(fbits(hi), fbits(lo), 0x07060302u);
}

// raw v_exp_f32 (args bounded; skips OCML range/subnormal fixup)
static __device__ __forceinline__ float fexp2(float x) {
#if __has_builtin(__builtin_amdgcn_exp2f)
  return __builtin_amdgcn_exp2f(x);
#else
  return exp2f(x);
#endif
}

static __device__ __forceinline__ void gload_lds16(const unsigned short* g, unsigned short* l) {
  __builtin_amdgcn_global_load_lds((const __attribute__((address_space(1))) void*)g,
                                   (__attribute__((address_space(3))) void*)l, 16, 0, 0);
}

// fp32 -> bf16 for x (4M), Wq,Wk,Wv,Wp (1M each), into contiguous dst.
__global__ __launch_bounds__(256) void convert_all(
    const float* __restrict__ x, const float* __restrict__ Wq,
    const float* __restrict__ Wk, const float* __restrict__ Wv,
    const float* __restrict__ Wp, unsigned short* __restrict__ dst)
{
  const size_t M4 = 4194304, M1 = 1048576;
  const size_t e = ((size_t)blockIdx.x * 256 + threadIdx.x) * 8;
  const float* src; size_t off;
  if (e < M4)            { src = x;  off = e; }
  else if (e < M4 + M1)  { src = Wq; off = e - M4; }
  else if (e < M4 + 2*M1){ src = Wk; off = e - M4 - M1; }
  else if (e < M4 + 3*M1){ src = Wv; off = e - M4 - 2*M1; }
  else                   { src = Wp; off = e - M4 - 3*M1; }
  float4 a = *(const float4*)(src + off);
  float4 c = *(const float4*)(src + off + 4);
  unsigned short buf[8] = {f2bf(a.x), f2bf(a.y), f2bf(a.z), f2bf(a.w),
                           f2bf(c.x), f2bf(c.y), f2bf(c.z), f2bf(c.w)};
  *(uint4*)(dst + e) = *(const uint4*)buf;
}

// ---------------------------------------------------------------------------
// R13: BK=32 double-buffered GEMM with COUNTED vmcnt (T4) + T2 swizzle.
//  - LDS back to 32 KB total (2 x 16 KB dbuf) -> 5 blocks/CU LDS-limit
//    (R12's 64 KB was the occupancy collapse).
//  - STAGE(kt+1) issued at top of iter kt; the matching wait is vmcnt(4)
//    (vmcnt(2) in proj) ONE FULL ITERATION later: loads fly across the
//    ds_read+16-MFMA cluster + 2 barriers. vmcnt(0) only on last iter.
//  - two raw s_barriers per K-step: leading (all waves' stage for buf[cur]
//    landed), trailing (all reads of buf[cur] drained before iter kt+1
//    re-stages it). lgkmcnt drain before trailing barrier comes free via
//    compiler waits on MFMA operands.
//  - swizzle (proven R12: conflicts 3.1M -> 0): phys chunk = logical ^
//    ((row>>1)&3) at 64 B rows; applied on the global SOURCE (LDS dest of
//    global_load_lds must stay linear) and on the ds_read address.
// ---------------------------------------------------------------------------

// bf16 MFMA GEMM for fused QKV. grid (32,24), 256 threads.
__global__ __launch_bounds__(256) void gemm_mfma(
    const unsigned short* __restrict__ A, const unsigned short* __restrict__ W,
    const float* __restrict__ b0, const float* __restrict__ b1, const float* __restrict__ b2,
    unsigned short* __restrict__ oQ, unsigned short* __restrict__ oK,
    unsigned short* __restrict__ oVt)
{
  __shared__ unsigned short As[2][128][32];
  __shared__ unsigned short Bs[2][128][32];
  const int t = threadIdx.x;
  const int wv = __builtin_amdgcn_readfirstlane(t >> 6);
  const int ln = t & 63;
  const int l16 = ln & 15;
  const int quad = ln >> 4;
  const int mBase = blockIdx.x * 128;
  const int nBase = blockIdx.y * 128;
  const int wm = (wv >> 1) * 64, wn = (wv & 1) * 64;

  f32x4 acc[4][4];
#pragma unroll
  for (int i = 0; i < 4; i++)
#pragma unroll
    for (int j = 0; j < 4; j++) acc[i][j] = (f32x4){0.f, 0.f, 0.f, 0.f};

  // staging: thread t -> row t>>2 (and +64 on the 2nd issue), phys chunk t&3.
  // source column pre-swizzled: logical chunk = (t&3) ^ ((row>>1)&3), with
  // (row>>1)&3 == (t>>3)&3 for both row halves.
  const int rloc = t >> 2;
  const int csrc = ((t & 3) ^ ((t >> 3) & 3)) * 8;
  const unsigned short* gA = A + (size_t)(mBase + rloc) * CC + csrc;
  const unsigned short* gB = W + (size_t)(nBase + rloc) * CC + csrc;
  // ds_read swizzle: row = wm|wn + i*16 + l16 -> (row>>1)&3 == (l16>>1)&3
  const int sw = (quad ^ ((l16 >> 1) & 3)) * 8;

#define STAGE(b, kt)                                                       \
  do {                                                                     \
    const size_t ko = (size_t)(kt) * 32;                                   \
    gload_lds16(gA + ko,               &As[b][0][0] + t * 8);              \
    gload_lds16(gA + ko + 64 * CC,     &As[b][64][0] + t * 8);             \
    gload_lds16(gB + ko,               &Bs[b][0][0] + t * 8);              \
    gload_lds16(gB + ko + 64 * CC,     &Bs[b][64][0] + t * 8);             \
  } while (0)

  STAGE(0, 0);
  for (int kt = 0; kt < 32; ++kt) {
    const int cur = kt & 1;
    if (kt < 31) {
      STAGE(cur ^ 1, kt + 1);
      asm volatile("s_waitcnt vmcnt(4)" ::: "memory");
    } else {
      asm volatile("s_waitcnt vmcnt(0)" ::: "memory");
    }
    __builtin_amdgcn_s_barrier();
    asm volatile("" ::: "memory");
    bf16x8 af[4], bfr[4];
#pragma unroll
    for (int i = 0; i < 4; ++i) af[i] = *(const bf16x8*)&As[cur][wm + i * 16 + l16][sw];
#pragma unroll
    for (int j = 0; j < 4; ++j) bfr[j] = *(const bf16x8*)&Bs[cur][wn + j * 16 + l16][sw];
    __builtin_amdgcn_s_setprio(1);
#pragma unroll
    for (int i = 0; i < 4; ++i)
#pragma unroll
      for (int j = 0; j < 4; ++j)
        acc[i][j] = __builtin_amdgcn_mfma_f32_16x16x32_bf16(af[i], bfr[j], acc[i][j], 0, 0, 0);
    __builtin_amdgcn_s_setprio(0);
    asm volatile("" ::: "memory");
    __builtin_amdgcn_s_barrier();
    asm volatile("" ::: "memory");
  }
#undef STAGE

  const int which = nBase >> 10;
  const float* bias = which == 0 ? b0 : (which == 1 ? b1 : b2);
  unsigned short* dst = which == 0 ? oQ : (which == 1 ? oK : oVt);
  const float scl = which == 0 ? 0.1803368801f : 1.0f;  // 0.125*log2(e) on Q
#pragma unroll
  for (int i = 0; i < 4; i++)
#pragma unroll
    for (int r = 0; r < 4; r++) {
      const int m = mBase + wm + i * 16 + quad * 4 + r;
      const int b = m >> 11, tp = m & 2047;
#pragma unroll
      for (int j = 0; j < 4; j++) {
        const int n = nBase + wn + j * 16 + l16;
        const int nl = n & 1023, h = nl >> 6, d = nl & 63;
        const unsigned short v = f2bf((acc[i][j][r] + bias[nl]) * scl);
        if (which < 2) dst[((size_t)(b * HH + h) * TT + tp) * HDD + d] = v;
        else           dst[((size_t)(b * HH + h) * HDD + d) * TT + tp] = v;
      }
    }
}

// Output projection: 128x128 tile, BK=32 dbuf, 512 threads, grid (32,8).
__global__ __launch_bounds__(512) void gemm_proj(
    const unsigned short* __restrict__ A, const unsigned short* __restrict__ W,
    const float* __restrict__ bias, float* __restrict__ out)
{
  __shared__ unsigned short As[2][128][32];
  __shared__ unsigned short Bs[2][128][32];
  const int t = threadIdx.x;
  const int wv = __builtin_amdgcn_readfirstlane(t >> 6);  // 0..7
  const int ln = t & 63;
  const int l16 = ln & 15;
  const int quad = ln >> 4;
  const int mBase = blockIdx.x * 128;
  const int nBase = blockIdx.y * 128;
  const int wm = (wv >> 2) * 64;        // {0,64}
  const int wn = (wv & 3) * 32;         // {0,32,64,96}

  f32x4 acc[4][2];
#pragma unroll
  for (int i = 0; i < 4; i++)
#pragma unroll
    for (int j = 0; j < 2; j++) acc[i][j] = (f32x4){0.f, 0.f, 0.f, 0.f};

  // staging: 512 threads cover a full 128x32 tile in ONE issue per matrix.
  const int rloc = t >> 2;                               // 0..127
  const int csrc = ((t & 3) ^ ((t >> 3) & 3)) * 8;
  const unsigned short* gA = A + (size_t)(mBase + rloc) * CC + csrc;
  const unsigned short* gB = W + (size_t)(nBase + rloc) * CC + csrc;
  const int sw = (quad ^ ((l16 >> 1) & 3)) * 8;

#define STAGE(b, kt)                                                       \
  do {                                                                     \
    const size_t ko = (size_t)(kt) * 32;                                   \
    gload_lds16(gA + ko, &As[b][0][0] + t * 8);                            \
    gload_lds16(gB + ko, &Bs[b][0][0] + t * 8);                            \
  } while (0)

  STAGE(0, 0);
  for (int kt = 0; kt < 32; ++kt) {
    const int cur = kt & 1;
    if (kt < 31) {
      STAGE(cur ^ 1, kt + 1);
      asm volatile("s_waitcnt vmcnt(2)" ::: "memory");
    } else {
      asm volatile("s_waitcnt vmcnt(0)" ::: "memory");
    }
    __builtin_amdgcn_s_barrier();
    asm volatile("" ::: "memory");
    bf16x8 af[4], bfr[2];
#pragma unroll
    for (int i = 0; i < 4; ++i) af[i] = *(const bf16x8*)&As[cur][wm + i * 16 + l16][sw];
#pragma unroll
    for (int j = 0; j < 2; ++j) bfr[j] = *(const bf16x8*)&Bs[cur][wn + j * 16 + l16][sw];
    __builtin_amdgcn_s_setprio(1);
#pragma unroll
    for (int i = 0; i < 4; ++i)
#pragma unroll
      for (int j = 0; j < 2; ++j)
        acc[i][j] = __builtin_amdgcn_mfma_f32_16x16x32_bf16(af[i], bfr[j], acc[i][j], 0, 0, 0);
    __builtin_amdgcn_s_setprio(0);
    asm volatile("" ::: "memory");
    __builtin_amdgcn_s_barrier();
    asm volatile("" ::: "memory");
  }
#undef STAGE

#pragma unroll
  for (int i = 0; i < 4; i++)
#pragma unroll
    for (int r = 0; r < 4; r++) {
      const int m = mBase + wm + i * 16 + quad * 4 + r;
#pragma unroll
      for (int j = 0; j < 2; j++) {
        const int n = nBase + wn + j * 16 + l16;
        out[(size_t)m * CC + n] = acc[i][j][r] + bias[n];
      }
    }
}

// MFMA bf16 flash attention — R7 paired structure (unchanged this round).
__global__ __launch_bounds__(256, 2) void attn_mfma(
    const unsigned short* __restrict__ Q, const unsigned short* __restrict__ K,
    const unsigned short* __restrict__ Vt, unsigned short* __restrict__ y)
{
  __shared__ unsigned short QP[128][72];      // Q tiles; becomes P after qfrag extract
  __shared__ unsigned short Ks[2][64][72];
  __shared__ unsigned short Vts[2][64][72];

  const int t = threadIdx.x;
  const int a = blockIdx.x;        // 0..15
  const int bh = blockIdx.y;       // 0..31
  const int wave = t >> 6;
  const int lane = t & 63;
  const int l16 = lane & 15;
  const int quad = lane >> 4;

  const size_t base = (size_t)bh * TT * HDD;
  const int qtL = a, qtH = 31 - a;
  const int qBaseL = qtL * 64, qBaseH = qtH * 64;

  // stage Q: rows 0..63 = lo tile, 64..127 = hi tile
#pragma unroll
  for (int p = 0; p < 4; p++) {
    const int c = p * 256 + t;
    const int r = c >> 3, off = (c & 7) * 8;
    const int srcRow = (r < 64) ? (qBaseL + r) : (qBaseH + r - 64);
    *(uint4*)&QP[r][off] = *(const uint4*)(Q + base + (size_t)srcRow * HDD + off);
  }

  // K/V register prefetch (tile 0)
  const int sr = t >> 2, sc = (t & 3) * 8;
  const unsigned short* kbase = K + base + (size_t)sr * HDD + sc;
  const unsigned short* vbase = Vt + base + (size_t)sr * TT + sc;
  uint4 kr0 = *(const uint4*)(kbase);
  uint4 kr1 = *(const uint4*)(kbase + 32);
  uint4 vr0 = *(const uint4*)(vbase);
  uint4 vr1 = *(const uint4*)(vbase + 32);
  __syncthreads();  // Q staged

  bf16x8 qfL0 = *(const bf16x8*)&QP[wave * 16 + l16][quad * 8];
  bf16x8 qfL1 = *(const bf16x8*)&QP[wave * 16 + l16][32 + quad * 8];
  bf16x8 qfH0 = *(const bf16x8*)&QP[64 + wave * 16 + l16][quad * 8];
  bf16x8 qfH1 = *(const bf16x8*)&QP[64 + wave * 16 + l16][32 + quad * 8];
  unsigned short (*PtH)[72] = (unsigned short (*)[72])&QP[wave * 16];
  unsigned short (*PtL)[72] = (unsigned short (*)[72])&QP[64 + wave * 16];

  float lL = 0.f, lH = 0.f;  // per-lane partial; cross-quad reduce deferred
  f32x4 OfrL[4], OfrH[4];
#pragma unroll
  for (int dt = 0; dt < 4; dt++) {
    OfrL[dt] = (f32x4){0.f, 0.f, 0.f, 0.f};
    OfrH[dt] = (f32x4){0.f, 0.f, 0.f, 0.f};
  }

  for (int kt = 0; kt <= qtH; kt++) {
    const int buf = kt & 1;
    *(uint4*)&Ks[buf][sr][sc]       = kr0;
    *(uint4*)&Ks[buf][sr][sc + 32]  = kr1;
    *(uint4*)&Vts[buf][sr][sc]      = vr0;
    *(uint4*)&Vts[buf][sr][sc + 32] = vr1;
    __syncthreads();  // ONLY barrier: commits visible; prior-buf readers done
    if (kt < qtH) {
      kr0 = *(const uint4*)(kbase + (size_t)(kt + 1) * 64 * HDD);
      kr1 = *(const uint4*)(kbase + (size_t)(kt + 1) * 64 * HDD + 32);
      vr0 = *(const uint4*)(vbase + (kt + 1) * 64);
      vr1 = *(const uint4*)(vbase + (kt + 1) * 64 + 32);
    }
    const bool doLo = (kt <= qtL);

    // S^T = K Q^T
    f32x4 StH[4], StL[4];
#pragma unroll
    for (int ct = 0; ct < 4; ct++) {
      bf16x8 a0 = *(const bf16x8*)&Ks[buf][ct * 16 + l16][quad * 8];
      bf16x8 a1 = *(const bf16x8*)&Ks[buf][ct * 16 + l16][32 + quad * 8];
      f32x4 s = (f32x4){0.f, 0.f, 0.f, 0.f};
      s = __builtin_amdgcn_mfma_f32_16x16x32_bf16(a0, qfH0, s, 0, 0, 0);
      s = __builtin_amdgcn_mfma_f32_16x16x32_bf16(a1, qfH1, s, 0, 0, 0);
      StH[ct] = s;
      if (doLo) {
        f32x4 s2 = (f32x4){0.f, 0.f, 0.f, 0.f};
        s2 = __builtin_amdgcn_mfma_f32_16x16x32_bf16(a0, qfL0, s2, 0, 0, 0);
        s2 = __builtin_amdgcn_mfma_f32_16x16x32_bf16(a1, qfL1, s2, 0, 0, 0);
        StL[ct] = s2;
      }
    }

    // softmax hi (mask only on the diagonal iteration — wave-uniform branch)
    if (kt == qtH) {
#pragma unroll
      for (int ct = 0; ct < 4; ct++) {
        float p[4];
#pragma unroll
        for (int r = 0; r < 4; r++) {
          float pv = fexp2(StH[ct][r]);
          if (ct * 16 + quad * 4 + r > wave * 16 + l16) pv = 0.f;
          p[r] = pv;
        }
        lH += (p[0] + p[1]) + (p[2] + p[3]);
        uint2 pk = {pk_trunc(p[0], p[1]), pk_trunc(p[2], p[3])};
        *(uint2*)&PtH[l16][ct * 16 + quad * 4] = pk;
      }
    } else {
#pragma unroll
      for (int ct = 0; ct < 4; ct++) {
        float p[4];
#pragma unroll
        for (int r = 0; r < 4; r++) p[r] = fexp2(StH[ct][r]);
        lH += (p[0] + p[1]) + (p[2] + p[3]);
        uint2 pk = {pk_trunc(p[0], p[1]), pk_trunc(p[2], p[3])};
        *(uint2*)&PtH[l16][ct * 16 + quad * 4] = pk;
      }
    }
    if (doLo) {
      if (kt == qtL) {
#pragma unroll
        for (int ct = 0; ct < 4; ct++) {
          float p[4];
#pragma unroll
          for (int r = 0; r < 4; r++) {
            float pv = fexp2(StL[ct][r]);
            if (ct * 16 + quad * 4 + r > wave * 16 + l16) pv = 0.f;
            p[r] = pv;
          }
          lL += (p[0] + p[1]) + (p[2] + p[3]);
          uint2 pk = {pk_trunc(p[0], p[1]), pk_trunc(p[2], p[3])};
          *(uint2*)&PtL[l16][ct * 16 + quad * 4] = pk;
        }
      } else {
#pragma unroll
        for (int ct = 0; ct < 4; ct++) {
          float p[4];
#pragma unroll
          for (int r = 0; r < 4; r++) p[r] = fexp2(StL[ct][r]);
          lL += (p[0] + p[1]) + (p[2] + p[3]);
          uint2 pk = {pk_trunc(p[0], p[1]), pk_trunc(p[2], p[3])};
          *(uint2*)&PtL[l16][ct * 16 + quad * 4] = pk;
        }
      }
    }

    // O += P V (Pt wave-private: in-wave lgkmcnt ordering, no barrier)
    bf16x8 paH0 = *(const bf16x8*)&PtH[l16][quad * 8];
    bf16x8 paH1 = *(const bf16x8*)&PtH[l16][32 + quad * 8];
    bf16x8 paL0, paL1;
    if (doLo) {
      paL0 = *(const bf16x8*)&PtL[l16][quad * 8];
      paL1 = *(const bf16x8*)&PtL[l16][32 + quad * 8];
    }
#pragma unroll
    for (int dt = 0; dt < 4; dt++) {
      bf16x8 vb0 = *(const bf16x8*)&Vts[buf][dt * 16 + l16][quad * 8];
      bf16x8 vb1 = *(const bf16x8*)&Vts[buf][dt * 16 + l16][32 + quad * 8];
      OfrH[dt] = __builtin_amdgcn_mfma_f32_16x16x32_bf16(paH0, vb0, OfrH[dt], 0, 0, 0);
      OfrH[dt] = __builtin_amdgcn_mfma_f32_16x16x32_bf16(paH1, vb1, OfrH[dt], 0, 0, 0);
      if (doLo) {
        OfrL[dt] = __builtin_amdgcn_mfma_f32_16x16x32_bf16(paL0, vb0, OfrL[dt], 0, 0, 0);
        OfrL[dt] = __builtin_amdgcn_mfma_f32_16x16x32_bf16(paL1, vb1, OfrL[dt], 0, 0, 0);
      }
    }
    // no trailing barrier: next iter commits the OTHER buffer
  }

  // deferred cross-quad l reduction
  lL += __shfl_xor(lL, 16, 64); lL += __shfl_xor(lL, 32, 64);
  lH += __shfl_xor(lH, 16, 64); lH += __shfl_xor(lH, 32, 64);

  const int b = bh >> 4, h = bh & 15;
  float lRowL[4], lRowH[4];
#pragma unroll
  for (int r = 0; r < 4; r++) {
    lRowL[r] = __shfl(lL, quad * 4 + r, 16);
    lRowH[r] = __shfl(lH, quad * 4 + r, 16);
  }
#pragma unroll
  for (int r = 0; r < 4; r++) {
    const int qL = qBaseL + wave * 16 + quad * 4 + r;
    const int qH = qBaseH + wave * 16 + quad * 4 + r;
    const float invL = 1.0f / lRowL[r];
    const float invH = 1.0f / lRowH[r];
    unsigned short* ypL = y + ((size_t)(b * TT + qL)) * CC + h * 64 + l16;
    unsigned short* ypH = y + ((size_t)(b * TT + qH)) * CC + h * 64 + l16;
#pragma unroll
    for (int dt = 0; dt < 4; dt++) {
      ypL[dt * 16] = f2bf(OfrL[dt][r] * invL);
      ypH[dt * 16] = f2bf(OfrH[dt][r] * invH);
    }
  }
}

extern "C" void kernel_launch(void* const* d_in, const int* in_sizes, int n_in,
                              void* d_out, int out_size, void* d_ws, size_t ws_size,
                              hipStream_t stream) {
  const float* x  = (const float*)d_in[0];
  const float* Wq = (const float*)d_in[1];
  const float* bq = (const float*)d_in[2];
  const float* Wk = (const float*)d_in[3];
  const float* bk = (const float*)d_in[4];
  const float* Wv = (const float*)d_in[5];
  const float* bv = (const float*)d_in[6];
  const float* Wp = (const float*)d_in[7];
  const float* bp = (const float*)d_in[8];

  const size_t M4 = 4194304, M1 = 1048576;
  unsigned short* xb   = (unsigned short*)d_ws;  // 4M
  unsigned short* wqb  = xb + M4;                // wq,wk,wv,wp contiguous
  unsigned short* wpb  = wqb + 3 * M1;
  unsigned short* wsQ  = wpb + M1;               // [B,H,T,HD] (pre-scaled)
  unsigned short* wsK  = wsQ + M4;               // [B,H,T,HD]
  unsigned short* wsVt = wsK + M4;               // [B,H,HD,T]
  unsigned short* yb   = wsVt + M4;              // [B,T,C] bf16

  convert_all<<<4096, 256, 0, stream>>>(x, Wq, Wk, Wv, Wp, xb);
  gemm_mfma<<<dim3(32, 24), 256, 0, stream>>>(xb, wqb, bq, bk, bv,
                                              wsQ, wsK, wsVt);
  attn_mfma<<<dim3(16, BB * HH), 256, 0, stream>>>(wsQ, wsK, wsVt, yb);
  gemm_proj<<<dim3(32, 8), 512, 0, stream>>>(yb, wpb, bp, (float*)d_out);
}